// Round 12
// baseline (1272.351 us; speedup 1.0000x reference)
//
#include <hip/hip_runtime.h>
#include <cmath>

#define T_STEPS 512
#define BATCH   64
#define ISZ     512
#define HSZ     512
#define EXN     32768   // u64 words per ring slot (64 batches x 512)

// ---------------------------------------------------------------------------
// Adaptive dual-medium tagged-word exchange. u64 = {tag=t+1 (hi32), h (lo32)}.
//  exF (ws[0..2*EXN))      L2 medium: store sc0 (SE scope: write-through L1
//                          into the shared XCD L2), poll sc0 (bypass L1, read
//                          L2). Valid when producer+consumer share an XCD --
//                          bid&7 clustering, PROVEN co-XCD by R2's 7.4x FETCH
//                          cut. ~250cyc RT vs ~900 for MALL.
//  exS (ws[2*EXN..4*EXN))  MALL medium: agent-scope atomics (R4 protocol,
//                          placement-independent, proven).
// Consumer: sticky per-thread fastmode -- sc0-only spin (NO MALL loads in
// flight, so the accept never waits on a MALL RT) up to 20 tries; on exhaust
// fall to the verbatim R4 atomic spin, permanently. Graceful: if the L2
// medium is dead, cost is one ~6k-cyc probe at t=1, then == R4.
// R10's confound (every accept drained in-flight MALL loads; safety probed
// only every 4th iter + sleep) is removed -- this cleanly measures the medium.
// ---------------------------------------------------------------------------
__device__ __forceinline__ void ex_store_dual(unsigned long long* wf,
                                              unsigned long long* ws,
                                              float h, unsigned tag) {
    union { float f; unsigned u; } c; c.f = h;
    const unsigned long long v = ((unsigned long long)tag << 32) | (unsigned long long)c.u;
    asm volatile("global_store_dwordx2 %0, %1, off sc0" :: "v"(wf), "v"(v) : "memory");
    __hip_atomic_store(ws, v, __ATOMIC_RELAXED, __HIP_MEMORY_SCOPE_AGENT);
}

// Volatile-asm 16B load: pins weight panels (128 floats/thread budget; R6:
// 256 aborts RA). Proven harmless R4-R11.
__device__ __forceinline__ float4 ld_pin_f4(const float* p) {
    float4 v;
    asm volatile("global_load_dwordx4 %0, %1, off" : "=v"(v) : "v"(p));
    return v;
}

// ---------------------------------------------------------------------------
// 16-k-segment dot for 4 output rows x 2 batches, merging butterfly over the
// 32 ksegs (lane bits 0..4): 9 shfls. Lane kseg<8 ends with the full dot for
// row=((kseg>>1)&1)+2*((kseg>>2)&1), b=kseg&1. BYTE-IDENTICAL to the R4
// 1020us kernel. LDS layout: float4[base + kseg*5 + i] (5-f4 slot pad).
// ---------------------------------------------------------------------------
__device__ __forceinline__ float dot16_fold(const float4 (&W)[4][4],
                                            const float4* __restrict__ src,
                                            int parbase4, int kseg) {
    const float4* s0 = src + parbase4 + kseg * 5;   // batch 0
    const float4* s1 = s0 + 160;                    // batch 1
    float A0 = 0.f, A1 = 0.f, A2 = 0.f, A3 = 0.f;
    float B0 = 0.f, B1 = 0.f, B2 = 0.f, B3 = 0.f;
    #pragma unroll
    for (int i = 0; i < 4; ++i) {
        const float4 h0 = s0[i];
        const float4 h1 = s1[i];
        const float4 w0 = W[0][i], w1 = W[1][i], w2 = W[2][i], w3 = W[3][i];
        A0 = fmaf(w0.x, h0.x, A0); A0 = fmaf(w0.y, h0.y, A0);
        A0 = fmaf(w0.z, h0.z, A0); A0 = fmaf(w0.w, h0.w, A0);
        A1 = fmaf(w1.x, h0.x, A1); A1 = fmaf(w1.y, h0.y, A1);
        A1 = fmaf(w1.z, h0.z, A1); A1 = fmaf(w1.w, h0.w, A1);
        A2 = fmaf(w2.x, h0.x, A2); A2 = fmaf(w2.y, h0.y, A2);
        A2 = fmaf(w2.z, h0.z, A2); A2 = fmaf(w2.w, h0.w, A2);
        A3 = fmaf(w3.x, h0.x, A3); A3 = fmaf(w3.y, h0.y, A3);
        A3 = fmaf(w3.z, h0.z, A3); A3 = fmaf(w3.w, h0.w, A3);
        B0 = fmaf(w0.x, h1.x, B0); B0 = fmaf(w0.y, h1.y, B0);
        B0 = fmaf(w0.z, h1.z, B0); B0 = fmaf(w0.w, h1.w, B0);
        B1 = fmaf(w1.x, h1.x, B1); B1 = fmaf(w1.y, h1.y, B1);
        B1 = fmaf(w1.z, h1.z, B1); B1 = fmaf(w1.w, h1.w, B1);
        B2 = fmaf(w2.x, h1.x, B2); B2 = fmaf(w2.y, h1.y, B2);
        B2 = fmaf(w2.z, h1.z, B2); B2 = fmaf(w2.w, h1.w, B2);
        B3 = fmaf(w3.x, h1.x, B3); B3 = fmaf(w3.y, h1.y, B3);
        B3 = fmaf(w3.z, h1.z, B3); B3 = fmaf(w3.w, h1.w, B3);
    }
    const bool sb0 = (kseg & 1) != 0;
    const bool sb1 = (kseg & 2) != 0;
    const bool sb2 = (kseg & 4) != 0;
    const float u0 = (sb0 ? B0 : A0) + __shfl_xor(sb0 ? A0 : B0, 1, 64);
    const float u1 = (sb0 ? B1 : A1) + __shfl_xor(sb0 ? A1 : B1, 1, 64);
    const float u2 = (sb0 ? B2 : A2) + __shfl_xor(sb0 ? A2 : B2, 1, 64);
    const float u3 = (sb0 ? B3 : A3) + __shfl_xor(sb0 ? A3 : B3, 1, 64);
    const float w01 = (sb1 ? u1 : u0) + __shfl_xor(sb1 ? u0 : u1, 2, 64);
    const float w23 = (sb1 ? u3 : u2) + __shfl_xor(sb1 ? u2 : u3, 2, 64);
    float z = (sb2 ? w23 : w01) + __shfl_xor(sb2 ? w01 : w23, 4, 64);
    z += __shfl_xor(z, 8, 64);
    z += __shfl_xor(z, 16, 64);
    return z;
}

// ---------------------------------------------------------------------------
// Fused RNN: R4's proven 1020us skeleton (256 WGs = 32 pairs x 8 slices,
// 512 thr, 1 WG/CU, thread owns 4 rows x 16 k x 2 batches, weights pinned,
// parity LDS, one barrier/step, in-loop xw) with the adaptive dual-medium
// exchange. All structural diagnostics (R2/R7/R9/R11) left step time at
// ~2us: the MALL RT chain is the wall; this targets exactly that term.
// ---------------------------------------------------------------------------
__global__ __launch_bounds__(512, 2) void rnn_fused(const float* __restrict__ x,
                                                    const float* __restrict__ wih,
                                                    const float* __restrict__ whh,
                                                    float* __restrict__ out,
                                                    unsigned long long* __restrict__ ex) {
    __shared__ __align__(16) float hls[2560];   // [2 par][2 b][32 kseg][5 f4]
    __shared__ __align__(16) float xss[2560];   // same layout, x rows
    const float4* hl4 = (const float4*)hls;
    const float4* xs4 = (const float4*)xss;

    const int tid  = threadIdx.x;
    const int bid  = blockIdx.x;
    const int xcd  = bid & 7;             // XCD under round-robin dispatch
    const int ib   = bid >> 3;            // 0..31 within XCD
    const int p    = xcd * 4 + (ib & 3);  // batch pair (cluster co-XCD: R2)
    const int g    = ib >> 2;             // neuron slice 0..7
    const int kseg = tid & 31;
    const int jg   = tid >> 5;
    const int jb   = g * 64 + jg * 4;

    // ---- weight micro-panels: 4 rows x 16 k of W_hh and W_ih (128 f32) ----
    float4 wh[4][4], wi[4][4];
    #pragma unroll
    for (int r = 0; r < 4; ++r) {
        const float* hr = whh + (size_t)(jb + r) * HSZ + kseg * 16;
        const float* ir = wih + (size_t)(jb + r) * ISZ + kseg * 16;
        #pragma unroll
        for (int i = 0; i < 4; ++i) {
            wh[r][i] = ld_pin_f4(hr + 4 * i);
            wi[r][i] = ld_pin_f4(ir + 4 * i);
        }
    }
    asm volatile("s_waitcnt vmcnt(0)" ::: "memory");
    __builtin_amdgcn_sched_barrier(0);

    // exchange pointers: fast (L2) copies at +0, safety (MALL) at +2*EXN
    unsigned long long* exf0 = ex + (size_t)(2 * p + 0) * 512 + tid;
    unsigned long long* exf1 = ex + (size_t)(2 * p + 1) * 512 + tid;

    // hl scatter offset for polled word k=tid (float idx; b=1 adds 640)
    const int whf = (tid >> 4) * 20 + ((tid >> 2) & 3) * 4 + (tid & 3);

    // x staging role: thread covers (bx, io..io+1), coalesced float2
    const int bx = tid >> 8;
    const int io = (tid & 255) * 2;
    const int xf = bx * 640 + (io >> 4) * 20 + ((io >> 2) & 3) * 4 + (io & 3);
    const float* xsrc = x + (size_t)(2 * p + bx) * ISZ + io;

    // designated-lane roles (valid for kseg<8)
    const int row  = ((kseg >> 1) & 1) + 2 * ((kseg >> 2) & 1);
    const int br   = kseg & 1;
    const int outj = jb + row;
    const int outb = 2 * p + br;
    float* outp = out + (size_t)outb * HSZ + outj;                 // + t*B*H
    unsigned long long* exfself = ex + (size_t)outb * 512 + outj;  // fast copy
    unsigned long long* exsself = exfself + 2 * (size_t)EXN;       // MALL copy

    // ---- prologue: stage x(0) (par 0), compute xw(0) ----
    {
        const float2 v = *(const float2*)xsrc;
        *(float2*)&xss[xf] = v;
    }
    __syncthreads();
    float xwv = dot16_fold(wi, xs4, 0, kseg);

    int fastm = 1;   // sticky per-thread medium selector

    for (int t = 0; t < T_STEPS; ++t) {
        const int  parh4 = (t & 1) * 320;          // f4 base for hls
        const bool havex = (t < T_STEPS - 1);

        // issue x(t+1) prefetch early: latency hides under the poll
        float2 xv;
        if (havex) xv = *(const float2*)(xsrc + (size_t)(t + 1) * (BATCH * ISZ));

        if (t > 0) {
            const size_t soff = (size_t)((t - 1) & 1) * EXN;
            const unsigned long long* f0 = exf0 + soff;
            const unsigned long long* f1 = exf1 + soff;
            unsigned long long v0 = 0, v1 = 0;
            bool ok0 = false, ok1 = false;

            if (fastm) {
                // L2-medium spin: sc0 loads only -> nothing MALL-bound in
                // flight; accept is never gated by a 900-cyc drain.
                for (int k = 0; k < 20; ++k) {
                    unsigned long long a, b;
                    asm volatile(
                        "global_load_dwordx2 %0, %2, off sc0\n\t"
                        "global_load_dwordx2 %1, %3, off sc0\n\t"
                        "s_waitcnt vmcnt(0)"
                        : "=&v"(a), "=&v"(b) : "v"(f0), "v"(f1) : "memory");
                    if (!ok0 && (unsigned)(a >> 32) == (unsigned)t) { v0 = a; ok0 = true; }
                    if (!ok1 && (unsigned)(b >> 32) == (unsigned)t) { v1 = b; ok1 = true; }
                    if (ok0 && ok1) break;
                }
                if (!(ok0 && ok1)) fastm = 0;      // medium not delivering
            }
            if (!(ok0 && ok1)) {
                // verbatim R4 MALL spin (proven floor path)
                const unsigned long long* s0 = f0 + 2 * (size_t)EXN;
                const unsigned long long* s1 = f1 + 2 * (size_t)EXN;
                for (;;) {
                    unsigned long long c = __hip_atomic_load(s0, __ATOMIC_RELAXED,
                                                             __HIP_MEMORY_SCOPE_AGENT);
                    unsigned long long d = __hip_atomic_load(s1, __ATOMIC_RELAXED,
                                                             __HIP_MEMORY_SCOPE_AGENT);
                    if (!ok0 && (unsigned)(c >> 32) == (unsigned)t) { v0 = c; ok0 = true; }
                    if (!ok1 && (unsigned)(d >> 32) == (unsigned)t) { v1 = d; ok1 = true; }
                    if (ok0 && ok1) break;
                    __builtin_amdgcn_s_sleep(1);
                }
            }
            union { unsigned u; float f; } c0, c1;
            c0.u = (unsigned)v0; c1.u = (unsigned)v1;
            hls[parh4 * 4 + whf]       = c0.f;     // batch 0
            hls[parh4 * 4 + 640 + whf] = c1.f;     // batch 1
        }
        if (havex) *(float2*)&xss[((t + 1) & 1) * 1280 + xf] = xv;
        __syncthreads();                           // single barrier per step

        float acc = 0.f;
        if (t > 0)
            acc = dot16_fold(wh, hl4, parh4, kseg);

        if (kseg < 8) {                            // 8 designated lanes / 32
            const float a2 = acc + xwv;
            const float e  = __expf(2.f * a2);     // tanh = (e-1)/(e+1)
            const float hv = 1.f - 2.f / (e + 1.f);
            if (havex) {
                const size_t so = (size_t)(t & 1) * EXN;
                ex_store_dual(exfself + so, exsself + so, hv, (unsigned)(t + 1));
            }
            outp[(size_t)t * (BATCH * HSZ)] = hv;
            if (!havex)
                out[(size_t)T_STEPS * BATCH * HSZ + (size_t)outb * HSZ + outj] = hv;
        }

        // xw(t+1): independent of the exchange -> fills the propagation window
        if (havex)
            xwv = dot16_fold(wi, xs4, ((t + 1) & 1) * 320, kseg);
    }
}

// ---------------------------------------------------------------------------
extern "C" void kernel_launch(void* const* d_in, const int* in_sizes, int n_in,
                              void* d_out, int out_size, void* d_ws, size_t ws_size,
                              hipStream_t stream) {
    (void)in_sizes; (void)n_in; (void)out_size; (void)ws_size;
    const float* x   = (const float*)d_in[0];   // (512,64,512)
    const float* wih = (const float*)d_in[1];   // (512,512)
    const float* whh = (const float*)d_in[2];   // (512,512)
    float*       out = (float*)d_out;           // h_all (T,B,H) ++ h_last (B,H)
    unsigned long long* ex = (unsigned long long*)d_ws;   // 4*EXN u64 = 1 MB

    // zero BOTH exchange regions (fast + safety); harness poisons d_ws.
    (void)hipMemsetAsync(d_ws, 0, 4 * EXN * sizeof(unsigned long long), stream);

    hipLaunchKernelGGL(rnn_fused, dim3(256), dim3(512), 0, stream,
                       x, wih, whh, out, ex);
}